// Round 7
// baseline (698.612 us; speedup 1.0000x reference)
//
#include <hip/hip_runtime.h>

#define NN 100000
#define NE 800000
#define HID 256

typedef __attribute__((ext_vector_type(8))) short bf16x8;
typedef __attribute__((ext_vector_type(4))) float f32x4;
typedef __attribute__((ext_vector_type(4))) unsigned short us4;
typedef __attribute__((ext_vector_type(8))) unsigned short us8;

__device__ __forceinline__ float bf2f(unsigned short u) {
    return __uint_as_float(((unsigned)u) << 16);
}
__device__ __forceinline__ unsigned short f2bf(float f) {
    unsigned u = __float_as_uint(f);
    u += 0x7fffu + ((u >> 16) & 1u);   // RNE
    return (unsigned short)(u >> 16);
}
__device__ __forceinline__ float rlf(float v, int l) {
    return __int_as_float(__builtin_amdgcn_readlane(__float_as_int(v), l));
}

// direct global->LDS DMA, 16B/lane (wave-uniform LDS base + lane*16)
__device__ __forceinline__ void gload16(const unsigned short* g, unsigned short* l) {
    __builtin_amdgcn_global_load_lds(
        (const __attribute__((address_space(1))) unsigned int*)g,
        (__attribute__((address_space(3))) unsigned int*)l, 16, 0, 0);
}

// ---------- dtype probes: flags[0]=f32 world, flags[1]=edge is int64 ----------
__global__ void probe_kernel(const void* W1, const void* edge, int* flags) {
    __shared__ int s_f32, s_odd;
    if (threadIdx.x == 0) { s_f32 = 0; s_odd = 0; }
    __syncthreads();
    const unsigned short* wu = (const unsigned short*)W1;
    for (int i = threadIdx.x; i < 2048; i += 256) {
        float v = bf2f(wu[i]);
        if (!(fabsf(v) <= 1.0f)) atomicOr(&s_f32, 1);
    }
    const int* ei = (const int*)edge;
    for (int i = threadIdx.x; i < 512; i += 256) {
        if (ei[2 * i + 1] != 0) atomicOr(&s_odd, 1);
    }
    __syncthreads();
    if (threadIdx.x == 0) { flags[0] = s_f32; flags[1] = s_odd ? 0 : 1; }
}

__device__ __forceinline__ int get_edge(const void* edge, int e64, long long idx) {
    return e64 ? (int)((const long long*)edge)[idx] : ((const int*)edge)[idx];
}
__device__ __forceinline__ float get_f(const void* p, int f32, size_t idx) {
    return f32 ? ((const float*)p)[idx] : bf2f(((const unsigned short*)p)[idx]);
}

// ---------- CSR build ----------
__global__ void zero_kernel(int* deg, int n) {
    int i = blockIdx.x * 256 + threadIdx.x;
    if (i < n) deg[i] = 0;
}
__global__ void count_kernel(const void* __restrict__ edge, const int* __restrict__ flags,
                             int* __restrict__ deg, int e) {
    int i = blockIdx.x * 256 + threadIdx.x;
    if (i < e) atomicAdd(&deg[get_edge(edge, flags[1], (long long)NE + i)], 1);
}
__global__ void dinv_kernel(const int* __restrict__ deg, float* __restrict__ dinv, int n) {
    int i = blockIdx.x * 256 + threadIdx.x;
    if (i < n) dinv[i] = 1.0f / sqrtf((float)(deg[i] + 1));
}
__global__ void scanA_kernel(const int* __restrict__ deg, int* __restrict__ rp,
                             int* __restrict__ bsums, int n) {
    __shared__ int sd[256];
    int tid = threadIdx.x;
    int base = blockIdx.x * 1024 + tid * 4;
    int v[4]; int ts = 0;
    for (int j = 0; j < 4; ++j) { v[j] = (base + j < n) ? deg[base + j] : 0; ts += v[j]; }
    sd[tid] = ts;
    __syncthreads();
    for (int off = 1; off < 256; off <<= 1) {
        int t = (tid >= off) ? sd[tid - off] : 0;
        __syncthreads();
        sd[tid] += t;
        __syncthreads();
    }
    int run = sd[tid] - ts;
    for (int j = 0; j < 4; ++j) {
        if (base + j < n) rp[base + j] = run;
        run += v[j];
    }
    if (tid == 255) bsums[blockIdx.x] = sd[255];
}
__global__ void scanB_kernel(int* bsums, int nb) {
    __shared__ int sd[128];
    int tid = threadIdx.x;
    int v = (tid < nb) ? bsums[tid] : 0;
    sd[tid] = v;
    __syncthreads();
    for (int off = 1; off < 128; off <<= 1) {
        int t = (tid >= off) ? sd[tid - off] : 0;
        __syncthreads();
        sd[tid] += t;
        __syncthreads();
    }
    if (tid < nb) bsums[tid] = sd[tid] - v;
}
__global__ void scanC_kernel(int* __restrict__ rp, const int* __restrict__ bsums, int n) {
    int base = blockIdx.x * 1024 + threadIdx.x * 4;
    int off = bsums[blockIdx.x];
    for (int j = 0; j < 4; ++j)
        if (base + j < n) rp[base + j] += off;
}
// countdown fill (destroys deg; dinv already extracted)
__global__ void fill_kernel(const void* __restrict__ edge, const int* __restrict__ flags,
                            const int* __restrict__ rp, int* __restrict__ deg,
                            int* __restrict__ csr, int e) {
    int i = blockIdx.x * 256 + threadIdx.x;
    if (i >= e) return;
    int e64 = flags[1];
    int s = get_edge(edge, e64, i);
    int d = get_edge(edge, e64, (long long)NE + i);
    int slot = atomicAdd(&deg[d], -1) - 1;
    csr[rp[d] + slot] = s;
}

// ---------- cast x -> bf16 plane ----------
__global__ void cast_kernel(const void* __restrict__ x, const int* __restrict__ flags,
                            unsigned short* __restrict__ xb, int n4) {
    int i = blockIdx.x * 256 + threadIdx.x;
    if (i >= n4) return;
    size_t o = (size_t)i * 4;
    us4 out;
    if (flags[0]) {
        float4 v = *(const float4*)((const float*)x + o);
        out[0] = f2bf(v.x); out[1] = f2bf(v.y); out[2] = f2bf(v.z); out[3] = f2bf(v.w);
    } else {
        out = *(const us4*)((const unsigned short*)x + o);
    }
    *(us4*)(xb + o) = out;
}

// ---------- weight transpose + hi/lo split: W[k,256] -> Wh/Wl[n,K] ----------
__global__ void wsplit_kernel(const void* __restrict__ W, const int* __restrict__ flags,
                              unsigned short* __restrict__ Wh, unsigned short* __restrict__ Wl,
                              int K) {
    int k = blockIdx.x, n = threadIdx.x;
    float v = get_f(W, flags[0], (size_t)k * 256 + n);
    unsigned short h = f2bf(v);
    Wh[n * K + k] = h;
    Wl[n * K + k] = f2bf(v - bf2f(h));
}

// ---------- pre-aggregation: out[i] = dinv_i * sum_j dinv_j act[j] + dinv_i^2 act[i] ----------
// Persistent waves (2048 blocks x 4 waves). 16B/lane gathers: each LPR-lane
// sub-group reads a DIFFERENT edge's row (EPG edges per wave-load), doubling/
// quadrupling bytes-per-vmem-instruction vs the old 8B/4B loads (the measured
// limiter: 3.7 TB/s == the 8B/lane issue-rate ceiling). Edge idx/weight via
// readlane+select (register-only); partial sums combined once per node via
// shfl_xor. All acc indexing static (rule #20).
template <int CPL>
__global__ __launch_bounds__(256) void agg_kernel(
    const unsigned short* __restrict__ act, const int* __restrict__ csr,
    const int* __restrict__ rp, const float* __restrict__ dinv,
    unsigned short* __restrict__ out, int n) {
    const int W = CPL * 64;
    constexpr int LPR = CPL * 8;   // lanes per row (32 for CPL=4, 16 for CPL=2)
    constexpr int EPG = 64 / LPR;  // edges per wave-load group (2 or 4)
    int wave = threadIdx.x >> 6;
    int lane = threadIdx.x & 63;
    int gw = blockIdx.x * 4 + wave;
    int nw = gridDim.x * 4;
    int sub = lane / LPR;          // which edge of the group this lane serves
    int li  = lane % LPR;          // 8-col slot within the row

    for (int node = gw; node < n; node += nw) {
        float acc[8];
#pragma unroll
        for (int q = 0; q < 8; ++q) acc[q] = 0.f;

        int beg = rp[node];
        int end = (node == n - 1) ? NE : rp[node + 1];
        float dn = dinv[node];

        for (int base = beg; base < end; base += 64) {
            int cnt = min(64, end - base);
            // hoisted index+weight fetch for up to 64 edges (coalesced)
            int sv = 0; float dv = 0.f;
            if (base + lane < end) {
                sv = csr[base + lane];
                dv = dinv[sv];
            }
            int j = 0;
            if constexpr (EPG == 2) {
                // ---- main: 4 groups = 8 edges, 4 x 16B loads in flight ----
                for (; j + 8 <= cnt; j += 8) {
                    int s0 = __builtin_amdgcn_readlane(sv, j + 0);
                    int s1 = __builtin_amdgcn_readlane(sv, j + 1);
                    int s2 = __builtin_amdgcn_readlane(sv, j + 2);
                    int s3 = __builtin_amdgcn_readlane(sv, j + 3);
                    int s4 = __builtin_amdgcn_readlane(sv, j + 4);
                    int s5 = __builtin_amdgcn_readlane(sv, j + 5);
                    int s6 = __builtin_amdgcn_readlane(sv, j + 6);
                    int s7 = __builtin_amdgcn_readlane(sv, j + 7);
                    float w0 = rlf(dv, j + 0), w1 = rlf(dv, j + 1);
                    float w2 = rlf(dv, j + 2), w3 = rlf(dv, j + 3);
                    float w4 = rlf(dv, j + 4), w5 = rlf(dv, j + 5);
                    float w6 = rlf(dv, j + 6), w7 = rlf(dv, j + 7);
                    int   sA = sub ? s1 : s0;  float wA = sub ? w1 : w0;
                    int   sB = sub ? s3 : s2;  float wB = sub ? w3 : w2;
                    int   sC = sub ? s5 : s4;  float wC = sub ? w5 : w4;
                    int   sD = sub ? s7 : s6;  float wD = sub ? w7 : w6;
                    us8 hA = *(const us8*)(act + (size_t)sA * W + li * 8);
                    us8 hB = *(const us8*)(act + (size_t)sB * W + li * 8);
                    us8 hC = *(const us8*)(act + (size_t)sC * W + li * 8);
                    us8 hD = *(const us8*)(act + (size_t)sD * W + li * 8);
#pragma unroll
                    for (int q = 0; q < 8; ++q)
                        acc[q] += bf2f(hA[q]) * wA + bf2f(hB[q]) * wB +
                                  bf2f(hC[q]) * wC + bf2f(hD[q]) * wD;
                }
                // ---- 2-group step (4 edges) ----
                if (j + 4 <= cnt) {
                    int s0 = __builtin_amdgcn_readlane(sv, j + 0);
                    int s1 = __builtin_amdgcn_readlane(sv, j + 1);
                    int s2 = __builtin_amdgcn_readlane(sv, j + 2);
                    int s3 = __builtin_amdgcn_readlane(sv, j + 3);
                    float w0 = rlf(dv, j + 0), w1 = rlf(dv, j + 1);
                    float w2 = rlf(dv, j + 2), w3 = rlf(dv, j + 3);
                    int   sA = sub ? s1 : s0;  float wA = sub ? w1 : w0;
                    int   sB = sub ? s3 : s2;  float wB = sub ? w3 : w2;
                    us8 hA = *(const us8*)(act + (size_t)sA * W + li * 8);
                    us8 hB = *(const us8*)(act + (size_t)sB * W + li * 8);
#pragma unroll
                    for (int q = 0; q < 8; ++q)
                        acc[q] += bf2f(hA[q]) * wA + bf2f(hB[q]) * wB;
                    j += 4;
                }
                // ---- clamped tail groups ----
                for (; j < cnt; j += 2) {
                    int e = j + sub;
                    int ec = min(e, cnt - 1);
                    int s = __shfl(sv, ec);
                    float w = (e < cnt) ? __shfl(dv, ec) : 0.f;
                    us8 h = *(const us8*)(act + (size_t)s * W + li * 8);
#pragma unroll
                    for (int q = 0; q < 8; ++q) acc[q] += bf2f(h[q]) * w;
                }
            } else {   // EPG == 4 (CPL == 2)
                // ---- main: 4 groups = 16 edges, 4 x 16B loads in flight ----
                for (; j + 16 <= cnt; j += 16) {
                    us8 h[4]; float w[4];
#pragma unroll
                    for (int g = 0; g < 4; ++g) {
                        int jj = j + g * 4;
                        int s0 = __builtin_amdgcn_readlane(sv, jj + 0);
                        int s1 = __builtin_amdgcn_readlane(sv, jj + 1);
                        int s2 = __builtin_amdgcn_readlane(sv, jj + 2);
                        int s3 = __builtin_amdgcn_readlane(sv, jj + 3);
                        float w0 = rlf(dv, jj + 0), w1 = rlf(dv, jj + 1);
                        float w2 = rlf(dv, jj + 2), w3 = rlf(dv, jj + 3);
                        int   tA = (sub & 1) ? s1 : s0;
                        int   tB = (sub & 1) ? s3 : s2;
                        int   s  = (sub & 2) ? tB : tA;
                        float uA = (sub & 1) ? w1 : w0;
                        float uB = (sub & 1) ? w3 : w2;
                        w[g] = (sub & 2) ? uB : uA;
                        h[g] = *(const us8*)(act + (size_t)s * W + li * 8);
                    }
#pragma unroll
                    for (int q = 0; q < 8; ++q)
                        acc[q] += bf2f(h[0][q]) * w[0] + bf2f(h[1][q]) * w[1] +
                                  bf2f(h[2][q]) * w[2] + bf2f(h[3][q]) * w[3];
                }
                // ---- clamped tail groups (4 edges each) ----
                for (; j < cnt; j += 4) {
                    int e = j + sub;
                    int ec = min(e, cnt - 1);
                    int s = __shfl(sv, ec);
                    float w = (e < cnt) ? __shfl(dv, ec) : 0.f;
                    us8 h = *(const us8*)(act + (size_t)s * W + li * 8);
#pragma unroll
                    for (int q = 0; q < 8; ++q) acc[q] += bf2f(h[q]) * w;
                }
            }
        }

        // combine partial sums across edge sub-groups (same li)
#pragma unroll
        for (int q = 0; q < 8; ++q) {
            if constexpr (EPG == 4) acc[q] += __shfl_xor(acc[q], 16);
            acc[q] += __shfl_xor(acc[q], 32);
        }

        float dn2 = dn * dn;
        if constexpr (CPL == 4) {
            float vq[4];
#pragma unroll
            for (int q = 0; q < 4; ++q) vq[q] = sub ? acc[4 + q] : acc[q];
            int col0 = li * 8 + sub * 4;
            us4 hs = *(const us4*)(act + (size_t)node * W + col0);
            us4 ov;
#pragma unroll
            for (int q = 0; q < 4; ++q)
                ov[q] = f2bf(vq[q] * dn + bf2f(hs[q]) * dn2);
            *(us4*)(out + (size_t)node * W + col0) = ov;
        } else {
            float vq[2];
#pragma unroll
            for (int q = 0; q < 2; ++q) {
                float x0 = (sub & 1) ? acc[2 + q] : acc[q];
                float x1 = (sub & 1) ? acc[6 + q] : acc[4 + q];
                vq[q] = (sub & 2) ? x1 : x0;
            }
            int col0 = li * 8 + sub * 2;
            ushort2 hs = *(const ushort2*)(act + (size_t)node * W + col0);
            ushort2 ov;
            ov.x = f2bf(vq[0] * dn + bf2f(hs.x) * dn2);
            ov.y = f2bf(vq[1] * dn + bf2f(hs.y) * dn2);
            *(ushort2*)(out + (size_t)node * W + col0) = ov;
        }
    }
}

// ---------- GEMM: LDS double-buffered 2-phase (T3-minimum recipe) ----------
// out[:,col0:col0+128] = A[M,K] @ (Wh+Wl) + b.  col0 = blockIdx.y * 128.
// Per K-step: issue NEXT tile's 6 global_load_lds into buf^1, then ds_read +
// 32 MFMA from buf, then ONE __syncthreads (vmcnt(0)+lgkmcnt(0)+barrier).
#define BM 128
#define BK 32
#define PLANE (BM * BK)   // 4096 elems = 8 KB per plane per buffer

__global__ __launch_bounds__(256) void gemm_kernel(
    const unsigned short* __restrict__ A, int K,
    const unsigned short* __restrict__ Wh, const unsigned short* __restrict__ Wl,
    const void* __restrict__ bias, const int* __restrict__ flags,
    int relu, int is_final,
    unsigned short* __restrict__ outb, float* __restrict__ outf, int M) {
    __shared__ __align__(16) unsigned short Ah[2 * PLANE];
    __shared__ __align__(16) unsigned short Bh[2 * PLANE];
    __shared__ __align__(16) unsigned short Bl[2 * PLANE];

    int tid = threadIdx.x;
    int lane = tid & 63;
    int wave = tid >> 6;
    int wm = wave >> 1, wn = wave & 1;
    int row0 = blockIdx.x * BM;
    int col0 = blockIdx.y * 128;
    int f32 = flags[0];

    int srow = lane >> 2;
    int skq = (lane & 3) * 8;
    int ar0 = row0 + wave * 16 + srow;
    int ar1 = row0 + (wave + 4) * 16 + srow;
    ar0 = min(ar0, M - 1);
    ar1 = min(ar1, M - 1);
    const unsigned short* ag0 = A + (size_t)ar0 * K + skq;
    const unsigned short* ag1 = A + (size_t)ar1 * K + skq;
    const unsigned short* bhg0 = Wh + (size_t)(col0 + wave * 16 + srow) * K + skq;
    const unsigned short* bhg1 = Wh + (size_t)(col0 + (wave + 4) * 16 + srow) * K + skq;
    const unsigned short* blg0 = Wl + (size_t)(col0 + wave * 16 + srow) * K + skq;
    const unsigned short* blg1 = Wl + (size_t)(col0 + (wave + 4) * 16 + srow) * K + skq;
    int lo0 = wave * 512;
    int lo1 = (wave + 4) * 512;

    f32x4 acc[4][4];
    for (int mt = 0; mt < 4; ++mt)
        for (int nt = 0; nt < 4; ++nt)
            acc[mt][nt] = (f32x4){0.f, 0.f, 0.f, 0.f};

    // prologue: stage tile 0 into buf 0
    gload16(ag0,  &Ah[lo0]);  gload16(ag1,  &Ah[lo1]);
    gload16(bhg0, &Bh[lo0]);  gload16(bhg1, &Bh[lo1]);
    gload16(blg0, &Bl[lo0]);  gload16(blg1, &Bl[lo1]);
    ag0 += BK; ag1 += BK; bhg0 += BK; bhg1 += BK; blg0 += BK; blg1 += BK;
    __syncthreads();

    int nt_steps = K / BK;
    int kqf = (lane >> 4) * 8;
    for (int t = 0; t < nt_steps; ++t) {
        int cur = (t & 1) * PLANE;
        int nxt = PLANE - cur;
        if (t + 1 < nt_steps) {
            gload16(ag0,  &Ah[nxt + lo0]);  gload16(ag1,  &Ah[nxt + lo1]);
            gload16(bhg0, &Bh[nxt + lo0]);  gload16(bhg1, &Bh[nxt + lo1]);
            gload16(blg0, &Bl[nxt + lo0]);  gload16(blg1, &Bl[nxt + lo1]);
            ag0 += BK; ag1 += BK; bhg0 += BK; bhg1 += BK; blg0 += BK; blg1 += BK;
        }

        bf16x8 af[4], bhf[4], blf[4];
#pragma unroll
        for (int tt = 0; tt < 4; ++tt) {
            int ar = cur + (wm * 64 + tt * 16 + (lane & 15)) * BK + kqf;
            int br = cur + (wn * 64 + tt * 16 + (lane & 15)) * BK + kqf;
            af[tt]  = *(const bf16x8*)&Ah[ar];
            bhf[tt] = *(const bf16x8*)&Bh[br];
            blf[tt] = *(const bf16x8*)&Bl[br];
        }
#pragma unroll
        for (int mt = 0; mt < 4; ++mt)
#pragma unroll
            for (int ntt = 0; ntt < 4; ++ntt) {
                acc[mt][ntt] = __builtin_amdgcn_mfma_f32_16x16x32_bf16(af[mt], bhf[ntt], acc[mt][ntt], 0, 0, 0);
                acc[mt][ntt] = __builtin_amdgcn_mfma_f32_16x16x32_bf16(af[mt], blf[ntt], acc[mt][ntt], 0, 0, 0);
            }
        __syncthreads();
    }

    // C/D layout: col=lane&15 (+16*nt), row=(lane>>4)*4+i
    int wf32 = is_final && f32;
    for (int mt = 0; mt < 4; ++mt)
        for (int ntt = 0; ntt < 4; ++ntt) {
            int col = col0 + wn * 64 + ntt * 16 + (lane & 15);
            float bv = get_f(bias, f32, (size_t)col);
            int rbase = row0 + wm * 64 + mt * 16 + ((lane >> 4) << 2);
            for (int i = 0; i < 4; ++i) {
                int r = rbase + i;
                if (r < M) {
                    float v = acc[mt][ntt][i] + bv;
                    if (relu) v = fmaxf(v, 0.f);
                    if (wf32) outf[(size_t)r * HID + col] = v;
                    else outb[(size_t)r * HID + col] = f2bf(v);
                }
            }
        }
}

// ---------- launch ----------
extern "C" void kernel_launch(void* const* d_in, const int* in_sizes, int n_in,
                              void* d_out, int out_size, void* d_ws, size_t ws_size,
                              hipStream_t stream) {
    const void* x    = d_in[0];
    const void* edge = d_in[1];
    const void* W1   = d_in[2];
    const void* b1   = d_in[3];
    const void* W2   = d_in[4];
    const void* b2   = d_in[5];
    const void* W3   = d_in[6];
    const void* b3   = d_in[7];

    const int N = NN, E = NE;

    char* w = (char*)d_ws;
    auto carve = [&](size_t bytes) -> void* {
        void* p = (void*)w;
        w += (bytes + 255) & ~(size_t)255;
        return p;
    };
    int*   flags = (int*)carve(256);
    int*   deg   = (int*)carve((size_t)N * 4);
    float* dinv  = (float*)carve((size_t)N * 4);
    int*   rp    = (int*)carve((size_t)N * 4);
    int*   bsums = (int*)carve(512);
    int*   csr   = (int*)carve((size_t)E * 4);
    unsigned short* Wh = (unsigned short*)carve((size_t)256 * 256 * 2);
    unsigned short* Wl = (unsigned short*)carve((size_t)256 * 256 * 2);
    unsigned short* Agg = (unsigned short*)carve((size_t)N * HID * 2);  // 51.2 MB; total ~55.9 MB

    // d_out doubles as scratch until the final GEMM overwrites it:
    //   xb  = bf16 x [N,128] at d_out[0:25.6MB]  (consumed by L1 agg)
    //   act = bf16 [N,256]   at d_out[0:51.2MB]  (layer l output, consumed by layer l+1 agg)
    unsigned short* xb  = (unsigned short*)d_out;
    unsigned short* act = (unsigned short*)d_out;

    int gN = (N + 255) / 256;
    int gE = (E + 255) / 256;
    int nb = (N + 1023) / 1024;
    dim3 ggemm(782, 2);
    int gagg = 2048;   // persistent: 8 blocks/CU x 4 waves, grid-stride over nodes

    probe_kernel<<<1, 256, 0, stream>>>(W1, edge, flags);
    zero_kernel<<<gN, 256, 0, stream>>>(deg, N);
    count_kernel<<<gE, 256, 0, stream>>>(edge, flags, deg, E);
    dinv_kernel<<<gN, 256, 0, stream>>>(deg, dinv, N);
    scanA_kernel<<<nb, 256, 0, stream>>>(deg, rp, bsums, N);
    scanB_kernel<<<1, 128, 0, stream>>>(bsums, nb);
    scanC_kernel<<<nb, 256, 0, stream>>>(rp, bsums, N);
    fill_kernel<<<gE, 256, 0, stream>>>(edge, flags, rp, deg, csr, E);
    cast_kernel<<<(N * 128 / 4 + 255) / 256, 256, 0, stream>>>(x, flags, xb, N * 128 / 4);

    // ---- layer 1 (K=128) ----
    wsplit_kernel<<<128, 256, 0, stream>>>(W1, flags, Wh, Wl, 128);
    agg_kernel<2><<<gagg, 256, 0, stream>>>(xb, csr, rp, dinv, Agg, N);
    gemm_kernel<<<ggemm, 256, 0, stream>>>(Agg, 128, Wh, Wl, b1, flags, 1, 0, act, nullptr, N);

    // ---- layer 2 (K=256) ----
    wsplit_kernel<<<256, 256, 0, stream>>>(W2, flags, Wh, Wl, 256);
    agg_kernel<4><<<gagg, 256, 0, stream>>>(act, csr, rp, dinv, Agg, N);
    gemm_kernel<<<ggemm, 256, 0, stream>>>(Agg, 256, Wh, Wl, b2, flags, 1, 0, act, nullptr, N);

    // ---- layer 3 (K=256, final) ----
    wsplit_kernel<<<256, 256, 0, stream>>>(W3, flags, Wh, Wl, 256);
    agg_kernel<4><<<gagg, 256, 0, stream>>>(act, csr, rp, dinv, Agg, N);
    gemm_kernel<<<ggemm, 256, 0, stream>>>(Agg, 256, Wh, Wl, b3, flags, 0, 1,
                                           (unsigned short*)d_out, (float*)d_out, N);
}

// Round 8
// 636.701 us; speedup vs baseline: 1.0972x; 1.0972x over previous
//
#include <hip/hip_runtime.h>

#define NN 100000
#define NE 800000
#define HID 256

typedef __attribute__((ext_vector_type(8))) short bf16x8;
typedef __attribute__((ext_vector_type(4))) float f32x4;
typedef __attribute__((ext_vector_type(4))) unsigned short us4;

__device__ __forceinline__ float bf2f(unsigned short u) {
    return __uint_as_float(((unsigned)u) << 16);
}
__device__ __forceinline__ unsigned short f2bf(float f) {
    unsigned u = __float_as_uint(f);
    u += 0x7fffu + ((u >> 16) & 1u);   // RNE
    return (unsigned short)(u >> 16);
}

// direct global->LDS DMA, 16B/lane (wave-uniform LDS base + lane*16)
__device__ __forceinline__ void gload16(const unsigned short* g, unsigned short* l) {
    __builtin_amdgcn_global_load_lds(
        (const __attribute__((address_space(1))) unsigned int*)g,
        (__attribute__((address_space(3))) unsigned int*)l, 16, 0, 0);
}

// ---------- dtype probes: flags[0]=f32 world, flags[1]=edge is int64 ----------
__global__ void probe_kernel(const void* W1, const void* edge, int* flags) {
    __shared__ int s_f32, s_odd;
    if (threadIdx.x == 0) { s_f32 = 0; s_odd = 0; }
    __syncthreads();
    const unsigned short* wu = (const unsigned short*)W1;
    for (int i = threadIdx.x; i < 2048; i += 256) {
        float v = bf2f(wu[i]);
        if (!(fabsf(v) <= 1.0f)) atomicOr(&s_f32, 1);
    }
    const int* ei = (const int*)edge;
    for (int i = threadIdx.x; i < 512; i += 256) {
        if (ei[2 * i + 1] != 0) atomicOr(&s_odd, 1);
    }
    __syncthreads();
    if (threadIdx.x == 0) { flags[0] = s_f32; flags[1] = s_odd ? 0 : 1; }
}

__device__ __forceinline__ int get_edge(const void* edge, int e64, long long idx) {
    return e64 ? (int)((const long long*)edge)[idx] : ((const int*)edge)[idx];
}
__device__ __forceinline__ float get_f(const void* p, int f32, size_t idx) {
    return f32 ? ((const float*)p)[idx] : bf2f(((const unsigned short*)p)[idx]);
}

// ---------- CSR build ----------
__global__ void zero_kernel(int* deg, int n) {
    int i = blockIdx.x * 256 + threadIdx.x;
    if (i < n) deg[i] = 0;
}
__global__ void count_kernel(const void* __restrict__ edge, const int* __restrict__ flags,
                             int* __restrict__ deg, int e) {
    int i = blockIdx.x * 256 + threadIdx.x;
    if (i < e) atomicAdd(&deg[get_edge(edge, flags[1], (long long)NE + i)], 1);
}
__global__ void dinv_kernel(const int* __restrict__ deg, float* __restrict__ dinv, int n) {
    int i = blockIdx.x * 256 + threadIdx.x;
    if (i < n) dinv[i] = 1.0f / sqrtf((float)(deg[i] + 1));
}
__global__ void scanA_kernel(const int* __restrict__ deg, int* __restrict__ rp,
                             int* __restrict__ bsums, int n) {
    __shared__ int sd[256];
    int tid = threadIdx.x;
    int base = blockIdx.x * 1024 + tid * 4;
    int v[4]; int ts = 0;
    for (int j = 0; j < 4; ++j) { v[j] = (base + j < n) ? deg[base + j] : 0; ts += v[j]; }
    sd[tid] = ts;
    __syncthreads();
    for (int off = 1; off < 256; off <<= 1) {
        int t = (tid >= off) ? sd[tid - off] : 0;
        __syncthreads();
        sd[tid] += t;
        __syncthreads();
    }
    int run = sd[tid] - ts;
    for (int j = 0; j < 4; ++j) {
        if (base + j < n) rp[base + j] = run;
        run += v[j];
    }
    if (tid == 255) bsums[blockIdx.x] = sd[255];
}
__global__ void scanB_kernel(int* bsums, int nb) {
    __shared__ int sd[128];
    int tid = threadIdx.x;
    int v = (tid < nb) ? bsums[tid] : 0;
    sd[tid] = v;
    __syncthreads();
    for (int off = 1; off < 128; off <<= 1) {
        int t = (tid >= off) ? sd[tid - off] : 0;
        __syncthreads();
        sd[tid] += t;
        __syncthreads();
    }
    if (tid < nb) bsums[tid] = sd[tid] - v;
}
__global__ void scanC_kernel(int* __restrict__ rp, const int* __restrict__ bsums, int n) {
    int base = blockIdx.x * 1024 + threadIdx.x * 4;
    int off = bsums[blockIdx.x];
    for (int j = 0; j < 4; ++j)
        if (base + j < n) rp[base + j] += off;
}
// countdown fill (destroys deg; dinv already extracted)
__global__ void fill_kernel(const void* __restrict__ edge, const int* __restrict__ flags,
                            const int* __restrict__ rp, int* __restrict__ deg,
                            int* __restrict__ csr, int e) {
    int i = blockIdx.x * 256 + threadIdx.x;
    if (i >= e) return;
    int e64 = flags[1];
    int s = get_edge(edge, e64, i);
    int d = get_edge(edge, e64, (long long)NE + i);
    int slot = atomicAdd(&deg[d], -1) - 1;
    csr[rp[d] + slot] = s;
}

// ---------- cast x -> bf16 plane ----------
__global__ void cast_kernel(const void* __restrict__ x, const int* __restrict__ flags,
                            unsigned short* __restrict__ xb, int n4) {
    int i = blockIdx.x * 256 + threadIdx.x;
    if (i >= n4) return;
    size_t o = (size_t)i * 4;
    us4 out;
    if (flags[0]) {
        float4 v = *(const float4*)((const float*)x + o);
        out[0] = f2bf(v.x); out[1] = f2bf(v.y); out[2] = f2bf(v.z); out[3] = f2bf(v.w);
    } else {
        out = *(const us4*)((const unsigned short*)x + o);
    }
    *(us4*)(xb + o) = out;
}

// ---------- weight transpose + hi/lo split: W[k,256] -> Wh/Wl[n,K] ----------
__global__ void wsplit_kernel(const void* __restrict__ W, const int* __restrict__ flags,
                              unsigned short* __restrict__ Wh, unsigned short* __restrict__ Wl,
                              int K) {
    int k = blockIdx.x, n = threadIdx.x;
    float v = get_f(W, flags[0], (size_t)k * 256 + n);
    unsigned short h = f2bf(v);
    Wh[n * K + k] = h;
    Wl[n * K + k] = f2bf(v - bf2f(h));
}

// ---------- pre-aggregation: out[i] = dinv_i * sum_j dinv_j act[j] + dinv_i^2 act[i] ----------
// Persistent waves (2048 blocks x 4 waves), one node per wave per step.
// Index/weight chain hoisted: per node, one coalesced csr load + one dinv gather
// fills lane-registers; the edge loop gets src/weight via v_readlane (register-only),
// so row gathers are the ONLY loop memory ops and stream back-to-back.
// (R7's 16B/lane restructure regressed 76->102us — this R6 form is the measured
// best; ~3.7 TB/s is the random-512B-gather wall for this pattern.)
template <int CPL>
__global__ __launch_bounds__(256) void agg_kernel(
    const unsigned short* __restrict__ act, const int* __restrict__ csr,
    const int* __restrict__ rp, const float* __restrict__ dinv,
    unsigned short* __restrict__ out, int n) {
    const int W = CPL * 64;
    int wave = threadIdx.x >> 6;
    int lane = threadIdx.x & 63;
    int gw = blockIdx.x * 4 + wave;
    int nw = gridDim.x * 4;
    int c = lane * CPL;

    for (int node = gw; node < n; node += nw) {
        float acc[CPL];
#pragma unroll
        for (int j = 0; j < CPL; ++j) acc[j] = 0.f;

        int beg = rp[node];
        int end = (node == n - 1) ? NE : rp[node + 1];
        float dn = dinv[node];

        // self-row: issue early, consumed at the end
        us4 hs4; ushort2 hs2;
        if (CPL == 4) hs4 = *(const us4*)(act + (size_t)node * W + c);
        else          hs2 = *(const ushort2*)(act + (size_t)node * W + c);

        for (int base = beg; base < end; base += 64) {
            int cnt = min(64, end - base);
            // hoisted index+weight fetch for up to 64 edges
            int sv = 0; float dv = 0.f;
            if (base + lane < end) {
                sv = csr[base + lane];
                dv = dinv[sv];
            }
            int j = 0;
            for (; j + 3 < cnt; j += 4) {
                int s0 = __builtin_amdgcn_readlane(sv, j);
                int s1 = __builtin_amdgcn_readlane(sv, j + 1);
                int s2 = __builtin_amdgcn_readlane(sv, j + 2);
                int s3 = __builtin_amdgcn_readlane(sv, j + 3);
                float w0 = __int_as_float(__builtin_amdgcn_readlane(__float_as_int(dv), j));
                float w1 = __int_as_float(__builtin_amdgcn_readlane(__float_as_int(dv), j + 1));
                float w2 = __int_as_float(__builtin_amdgcn_readlane(__float_as_int(dv), j + 2));
                float w3 = __int_as_float(__builtin_amdgcn_readlane(__float_as_int(dv), j + 3));
                if (CPL == 4) {
                    us4 h0 = *(const us4*)(act + (size_t)s0 * W + c);
                    us4 h1 = *(const us4*)(act + (size_t)s1 * W + c);
                    us4 h2 = *(const us4*)(act + (size_t)s2 * W + c);
                    us4 h3 = *(const us4*)(act + (size_t)s3 * W + c);
#pragma unroll
                    for (int q = 0; q < 4; ++q)
                        acc[q] += bf2f(h0[q]) * w0 + bf2f(h1[q]) * w1 +
                                  bf2f(h2[q]) * w2 + bf2f(h3[q]) * w3;
                } else {
                    ushort2 h0 = *(const ushort2*)(act + (size_t)s0 * W + c);
                    ushort2 h1 = *(const ushort2*)(act + (size_t)s1 * W + c);
                    ushort2 h2 = *(const ushort2*)(act + (size_t)s2 * W + c);
                    ushort2 h3 = *(const ushort2*)(act + (size_t)s3 * W + c);
                    acc[0] += bf2f(h0.x) * w0 + bf2f(h1.x) * w1 + bf2f(h2.x) * w2 + bf2f(h3.x) * w3;
                    acc[1] += bf2f(h0.y) * w0 + bf2f(h1.y) * w1 + bf2f(h2.y) * w2 + bf2f(h3.y) * w3;
                }
            }
            if (j + 1 < cnt) {
                int s0 = __builtin_amdgcn_readlane(sv, j);
                int s1 = __builtin_amdgcn_readlane(sv, j + 1);
                float w0 = __int_as_float(__builtin_amdgcn_readlane(__float_as_int(dv), j));
                float w1 = __int_as_float(__builtin_amdgcn_readlane(__float_as_int(dv), j + 1));
                if (CPL == 4) {
                    us4 h0 = *(const us4*)(act + (size_t)s0 * W + c);
                    us4 h1 = *(const us4*)(act + (size_t)s1 * W + c);
#pragma unroll
                    for (int q = 0; q < 4; ++q)
                        acc[q] += bf2f(h0[q]) * w0 + bf2f(h1[q]) * w1;
                } else {
                    ushort2 h0 = *(const ushort2*)(act + (size_t)s0 * W + c);
                    ushort2 h1 = *(const ushort2*)(act + (size_t)s1 * W + c);
                    acc[0] += bf2f(h0.x) * w0 + bf2f(h1.x) * w1;
                    acc[1] += bf2f(h0.y) * w0 + bf2f(h1.y) * w1;
                }
                j += 2;
            }
            if (j < cnt) {
                int s0 = __builtin_amdgcn_readlane(sv, j);
                float w0 = __int_as_float(__builtin_amdgcn_readlane(__float_as_int(dv), j));
                if (CPL == 4) {
                    us4 h0 = *(const us4*)(act + (size_t)s0 * W + c);
#pragma unroll
                    for (int q = 0; q < 4; ++q) acc[q] += bf2f(h0[q]) * w0;
                } else {
                    ushort2 h0 = *(const ushort2*)(act + (size_t)s0 * W + c);
                    acc[0] += bf2f(h0.x) * w0;
                    acc[1] += bf2f(h0.y) * w0;
                }
            }
        }

        if (CPL == 4) {
            us4 ov;
#pragma unroll
            for (int j = 0; j < 4; ++j)
                ov[j] = f2bf(acc[j] * dn + bf2f(hs4[j]) * (dn * dn));
            *(us4*)(out + (size_t)node * W + c) = ov;
        } else {
            ushort2 ov;
            ov.x = f2bf(acc[0] * dn + bf2f(hs2.x) * (dn * dn));
            ov.y = f2bf(acc[1] * dn + bf2f(hs2.y) * (dn * dn));
            *(ushort2*)(out + (size_t)node * W + c) = ov;
        }
    }
}

// ---------- GEMM: 3-deep ring LDS pipeline with counted vmcnt (T4) ----------
// out[:,col0:col0+128] = A[M,K] @ (Wh+Wl) + b.  col0 = blockIdx.y * 128.
// Stages issued 3 K-steps ahead (6 gload_lds/wave/stage). Per step:
//   s_waitcnt vmcnt(12|6|0)  -> own stage-t loads retired (12 = 2 newer stages)
//   s_barrier                -> all waves' stage-t loads retired: buffer valid
//   ds_read buffer t%3 -> regs
//   s_waitcnt lgkmcnt(0) + sched_barrier -> reads complete (rule #18)
//   s_barrier                -> safe to overwrite slot t%3
//   issue stage t+3 into slot t%3 ; 32 MFMA (compiler interleaves)
// No vmcnt(0) in steady state: each stage has ~2 steps (>600cy) to land.
#define BM 128
#define BK 32
#define PLANE (BM * BK)   // 4096 elems = 8 KB per plane per buffer
#define NBUF 3

__global__ __launch_bounds__(256) void gemm_kernel(
    const unsigned short* __restrict__ A, int K,
    const unsigned short* __restrict__ Wh, const unsigned short* __restrict__ Wl,
    const void* __restrict__ bias, const int* __restrict__ flags,
    int relu, int is_final,
    unsigned short* __restrict__ outb, float* __restrict__ outf, int M) {
    __shared__ __align__(16) unsigned short Ah[NBUF * PLANE];
    __shared__ __align__(16) unsigned short Bh[NBUF * PLANE];
    __shared__ __align__(16) unsigned short Bl[NBUF * PLANE];

    int tid = threadIdx.x;
    int lane = tid & 63;
    int wave = tid >> 6;
    int wm = wave >> 1, wn = wave & 1;
    int row0 = blockIdx.x * BM;
    int col0 = blockIdx.y * 128;
    int f32 = flags[0];

    // staging geometry: chunk = 16 rows x 32 bf16 (1 KiB); lane l -> row l>>2,
    // 16B at bf16-offset (l&3)*8. Wave w stages chunks {w, w+4} of each plane.
    int srow = lane >> 2;
    int skq = (lane & 3) * 8;
    int ar0 = row0 + wave * 16 + srow;
    int ar1 = row0 + (wave + 4) * 16 + srow;
    ar0 = min(ar0, M - 1);
    ar1 = min(ar1, M - 1);
    const unsigned short* ag0 = A + (size_t)ar0 * K + skq;
    const unsigned short* ag1 = A + (size_t)ar1 * K + skq;
    const unsigned short* bhg0 = Wh + (size_t)(col0 + wave * 16 + srow) * K + skq;
    const unsigned short* bhg1 = Wh + (size_t)(col0 + (wave + 4) * 16 + srow) * K + skq;
    const unsigned short* blg0 = Wl + (size_t)(col0 + wave * 16 + srow) * K + skq;
    const unsigned short* blg1 = Wl + (size_t)(col0 + (wave + 4) * 16 + srow) * K + skq;
    int lo0 = wave * 512;
    int lo1 = (wave + 4) * 512;

    f32x4 acc[4][4];
    for (int mt = 0; mt < 4; ++mt)
        for (int nt = 0; nt < 4; ++nt)
            acc[mt][nt] = (f32x4){0.f, 0.f, 0.f, 0.f};

    int nsteps = K / BK;   // 4 or 8; always >= 3 stages prologue

    // prologue: stage tiles 0,1,2 into buffers 0,1,2 (18 loads/wave in flight)
#pragma unroll
    for (int s = 0; s < 3; ++s) {
        int off = s * PLANE;
        gload16(ag0,  &Ah[off + lo0]);  gload16(ag1,  &Ah[off + lo1]);
        gload16(bhg0, &Bh[off + lo0]);  gload16(bhg1, &Bh[off + lo1]);
        gload16(blg0, &Bl[off + lo0]);  gload16(blg1, &Bl[off + lo1]);
        ag0 += BK; ag1 += BK; bhg0 += BK; bhg1 += BK; blg0 += BK; blg1 += BK;
    }

    int kqf = (lane >> 4) * 8;
    for (int t = 0; t < nsteps; ++t) {
        int rem = nsteps - 1 - t;
        if (rem >= 2)      asm volatile("s_waitcnt vmcnt(12)" ::: "memory");
        else if (rem == 1) asm volatile("s_waitcnt vmcnt(6)"  ::: "memory");
        else               asm volatile("s_waitcnt vmcnt(0)"  ::: "memory");
        __builtin_amdgcn_s_barrier();
        asm volatile("" ::: "memory");   // keep ds_reads below the barrier

        int cur = (t % 3) * PLANE;
        bf16x8 af[4], bhf[4], blf[4];
#pragma unroll
        for (int tt = 0; tt < 4; ++tt) {
            int ar = cur + (wm * 64 + tt * 16 + (lane & 15)) * BK + kqf;
            int br = cur + (wn * 64 + tt * 16 + (lane & 15)) * BK + kqf;
            af[tt]  = *(const bf16x8*)&Ah[ar];
            bhf[tt] = *(const bf16x8*)&Bh[br];
            blf[tt] = *(const bf16x8*)&Bl[br];
        }
        asm volatile("s_waitcnt lgkmcnt(0)" ::: "memory");
        __builtin_amdgcn_sched_barrier(0);  // rule #18: no hoist past the wait
        __builtin_amdgcn_s_barrier();
        asm volatile("" ::: "memory");   // keep next-stage issues below barrier

        // overwrite slot t%3 with stage t+3 (all reads of it are complete)
        if (t + 3 < nsteps) {
            gload16(ag0,  &Ah[cur + lo0]);  gload16(ag1,  &Ah[cur + lo1]);
            gload16(bhg0, &Bh[cur + lo0]);  gload16(bhg1, &Bh[cur + lo1]);
            gload16(blg0, &Bl[cur + lo0]);  gload16(blg1, &Bl[cur + lo1]);
            ag0 += BK; ag1 += BK; bhg0 += BK; bhg1 += BK; blg0 += BK; blg1 += BK;
        }

#pragma unroll
        for (int mt = 0; mt < 4; ++mt)
#pragma unroll
            for (int ntt = 0; ntt < 4; ++ntt) {
                acc[mt][ntt] = __builtin_amdgcn_mfma_f32_16x16x32_bf16(af[mt], bhf[ntt], acc[mt][ntt], 0, 0, 0);
                acc[mt][ntt] = __builtin_amdgcn_mfma_f32_16x16x32_bf16(af[mt], blf[ntt], acc[mt][ntt], 0, 0, 0);
            }
    }

    // C/D layout: col=lane&15 (+16*nt), row=(lane>>4)*4+i
    int wf32 = is_final && f32;
    for (int mt = 0; mt < 4; ++mt)
        for (int ntt = 0; ntt < 4; ++ntt) {
            int col = col0 + wn * 64 + ntt * 16 + (lane & 15);
            float bv = get_f(bias, f32, (size_t)col);
            int rbase = row0 + wm * 64 + mt * 16 + ((lane >> 4) << 2);
            for (int i = 0; i < 4; ++i) {
                int r = rbase + i;
                if (r < M) {
                    float v = acc[mt][ntt][i] + bv;
                    if (relu) v = fmaxf(v, 0.f);
                    if (wf32) outf[(size_t)r * HID + col] = v;
                    else outb[(size_t)r * HID + col] = f2bf(v);
                }
            }
        }
}

// ---------- launch ----------
extern "C" void kernel_launch(void* const* d_in, const int* in_sizes, int n_in,
                              void* d_out, int out_size, void* d_ws, size_t ws_size,
                              hipStream_t stream) {
    const void* x    = d_in[0];
    const void* edge = d_in[1];
    const void* W1   = d_in[2];
    const void* b1   = d_in[3];
    const void* W2   = d_in[4];
    const void* b2   = d_in[5];
    const void* W3   = d_in[6];
    const void* b3   = d_in[7];

    const int N = NN, E = NE;

    char* w = (char*)d_ws;
    auto carve = [&](size_t bytes) -> void* {
        void* p = (void*)w;
        w += (bytes + 255) & ~(size_t)255;
        return p;
    };
    int*   flags = (int*)carve(256);
    int*   deg   = (int*)carve((size_t)N * 4);
    float* dinv  = (float*)carve((size_t)N * 4);
    int*   rp    = (int*)carve((size_t)N * 4);
    int*   bsums = (int*)carve(512);
    int*   csr   = (int*)carve((size_t)E * 4);
    unsigned short* Wh = (unsigned short*)carve((size_t)256 * 256 * 2);
    unsigned short* Wl = (unsigned short*)carve((size_t)256 * 256 * 2);
    unsigned short* Agg = (unsigned short*)carve((size_t)N * HID * 2);  // 51.2 MB; total ~55.9 MB

    // d_out doubles as scratch until the final GEMM overwrites it:
    //   xb  = bf16 x [N,128] at d_out[0:25.6MB]  (consumed by L1 agg)
    //   act = bf16 [N,256]   at d_out[0:51.2MB]  (layer l output, consumed by layer l+1 agg)
    unsigned short* xb  = (unsigned short*)d_out;
    unsigned short* act = (unsigned short*)d_out;

    int gN = (N + 255) / 256;
    int gE = (E + 255) / 256;
    int nb = (N + 1023) / 1024;
    dim3 ggemm(782, 2);
    int gagg = 2048;   // persistent: 8 blocks/CU x 4 waves, grid-stride over nodes

    probe_kernel<<<1, 256, 0, stream>>>(W1, edge, flags);
    zero_kernel<<<gN, 256, 0, stream>>>(deg, N);
    count_kernel<<<gE, 256, 0, stream>>>(edge, flags, deg, E);
    dinv_kernel<<<gN, 256, 0, stream>>>(deg, dinv, N);
    scanA_kernel<<<nb, 256, 0, stream>>>(deg, rp, bsums, N);
    scanB_kernel<<<1, 128, 0, stream>>>(bsums, nb);
    scanC_kernel<<<nb, 256, 0, stream>>>(rp, bsums, N);
    fill_kernel<<<gE, 256, 0, stream>>>(edge, flags, rp, deg, csr, E);
    cast_kernel<<<(N * 128 / 4 + 255) / 256, 256, 0, stream>>>(x, flags, xb, N * 128 / 4);

    // ---- layer 1 (K=128) ----
    wsplit_kernel<<<128, 256, 0, stream>>>(W1, flags, Wh, Wl, 128);
    agg_kernel<2><<<gagg, 256, 0, stream>>>(xb, csr, rp, dinv, Agg, N);
    gemm_kernel<<<ggemm, 256, 0, stream>>>(Agg, 128, Wh, Wl, b1, flags, 1, 0, act, nullptr, N);

    // ---- layer 2 (K=256) ----
    wsplit_kernel<<<256, 256, 0, stream>>>(W2, flags, Wh, Wl, 256);
    agg_kernel<4><<<gagg, 256, 0, stream>>>(act, csr, rp, dinv, Agg, N);
    gemm_kernel<<<ggemm, 256, 0, stream>>>(Agg, 256, Wh, Wl, b2, flags, 1, 0, act, nullptr, N);

    // ---- layer 3 (K=256, final) ----
    wsplit_kernel<<<256, 256, 0, stream>>>(W3, flags, Wh, Wl, 256);
    agg_kernel<4><<<gagg, 256, 0, stream>>>(act, csr, rp, dinv, Agg, N);
    gemm_kernel<<<ggemm, 256, 0, stream>>>(Agg, 256, Wh, Wl, b3, flags, 0, 1,
                                           (unsigned short*)d_out, (float*)d_out, N);
}

// Round 9
// 594.437 us; speedup vs baseline: 1.1752x; 1.0711x over previous
//
#include <hip/hip_runtime.h>

#define NN 100000
#define NE 800000
#define HID 256

typedef __attribute__((ext_vector_type(8))) short bf16x8;
typedef __attribute__((ext_vector_type(4))) float f32x4;
typedef __attribute__((ext_vector_type(4))) unsigned short us4;

__device__ __forceinline__ float bf2f(unsigned short u) {
    return __uint_as_float(((unsigned)u) << 16);
}
__device__ __forceinline__ unsigned short f2bf(float f) {
    unsigned u = __float_as_uint(f);
    u += 0x7fffu + ((u >> 16) & 1u);   // RNE
    return (unsigned short)(u >> 16);
}

// direct global->LDS DMA, 16B/lane (wave-uniform LDS base + lane*16)
__device__ __forceinline__ void gload16(const unsigned short* g, unsigned short* l) {
    __builtin_amdgcn_global_load_lds(
        (const __attribute__((address_space(1))) unsigned int*)g,
        (__attribute__((address_space(3))) unsigned int*)l, 16, 0, 0);
}

// ---------- dtype probes: flags[0]=f32 world, flags[1]=edge is int64 ----------
__global__ void probe_kernel(const void* W1, const void* edge, int* flags) {
    __shared__ int s_f32, s_odd;
    if (threadIdx.x == 0) { s_f32 = 0; s_odd = 0; }
    __syncthreads();
    const unsigned short* wu = (const unsigned short*)W1;
    for (int i = threadIdx.x; i < 2048; i += 256) {
        float v = bf2f(wu[i]);
        if (!(fabsf(v) <= 1.0f)) atomicOr(&s_f32, 1);
    }
    const int* ei = (const int*)edge;
    for (int i = threadIdx.x; i < 512; i += 256) {
        if (ei[2 * i + 1] != 0) atomicOr(&s_odd, 1);
    }
    __syncthreads();
    if (threadIdx.x == 0) { flags[0] = s_f32; flags[1] = s_odd ? 0 : 1; }
}

__device__ __forceinline__ int get_edge(const void* edge, int e64, long long idx) {
    return e64 ? (int)((const long long*)edge)[idx] : ((const int*)edge)[idx];
}
__device__ __forceinline__ float get_f(const void* p, int f32, size_t idx) {
    return f32 ? ((const float*)p)[idx] : bf2f(((const unsigned short*)p)[idx]);
}

// ---------- prep: zero deg (blocks 0..390) + cast x -> bf16 plane (all blocks) ----------
__global__ void prep_kernel(const void* __restrict__ x, const int* __restrict__ flags,
                            int* __restrict__ deg, unsigned short* __restrict__ xb, int n4) {
    int i = blockIdx.x * 256 + threadIdx.x;
    if (i < NN) deg[i] = 0;
    if (i >= n4) return;
    size_t o = (size_t)i * 4;
    us4 out;
    if (flags[0]) {
        float4 v = *(const float4*)((const float*)x + o);
        out[0] = f2bf(v.x); out[1] = f2bf(v.y); out[2] = f2bf(v.z); out[3] = f2bf(v.w);
    } else {
        out = *(const us4*)((const unsigned short*)x + o);
    }
    *(us4*)(xb + o) = out;
}

__global__ void count_kernel(const void* __restrict__ edge, const int* __restrict__ flags,
                             int* __restrict__ deg, int e) {
    int i = blockIdx.x * 256 + threadIdx.x;
    if (i < e) atomicAdd(&deg[get_edge(edge, flags[1], (long long)NE + i)], 1);
}

// scanA: block-local exclusive scan of deg into rp + block sums; also emits dinv
__global__ void scanA_kernel(const int* __restrict__ deg, int* __restrict__ rp,
                             int* __restrict__ bsums, float* __restrict__ dinv, int n) {
    __shared__ int sd[256];
    int tid = threadIdx.x;
    int base = blockIdx.x * 1024 + tid * 4;
    int v[4]; int ts = 0;
    for (int j = 0; j < 4; ++j) {
        v[j] = (base + j < n) ? deg[base + j] : 0;
        ts += v[j];
        if (base + j < n) dinv[base + j] = 1.0f / sqrtf((float)(v[j] + 1));
    }
    sd[tid] = ts;
    __syncthreads();
    for (int off = 1; off < 256; off <<= 1) {
        int t = (tid >= off) ? sd[tid - off] : 0;
        __syncthreads();
        sd[tid] += t;
        __syncthreads();
    }
    int run = sd[tid] - ts;
    for (int j = 0; j < 4; ++j) {
        if (base + j < n) rp[base + j] = run;
        run += v[j];
    }
    if (tid == 255) bsums[blockIdx.x] = sd[255];
}
// scanC': each block locally scans the (<=128) block sums, then offsets its rp range
__global__ void scanC_kernel(int* __restrict__ rp, const int* __restrict__ bsums,
                             int n, int nb) {
    __shared__ int sd[128];
    __shared__ int s_off;
    int tid = threadIdx.x;
    if (tid < 128) sd[tid] = (tid < nb) ? bsums[tid] : 0;
    __syncthreads();
    for (int off = 1; off < 128; off <<= 1) {
        int t = 0;
        if (tid < 128 && tid >= off) t = sd[tid - off];
        __syncthreads();
        if (tid < 128) sd[tid] += t;
        __syncthreads();
    }
    if (tid == 0) s_off = (blockIdx.x == 0) ? 0 : sd[blockIdx.x - 1];
    __syncthreads();
    int off = s_off;
    int base = blockIdx.x * 1024 + tid * 4;
    for (int j = 0; j < 4; ++j)
        if (base + j < n) rp[base + j] += off;
}
// countdown fill (destroys deg; dinv already extracted)
__global__ void fill_kernel(const void* __restrict__ edge, const int* __restrict__ flags,
                            const int* __restrict__ rp, int* __restrict__ deg,
                            int* __restrict__ csr, int e) {
    int i = blockIdx.x * 256 + threadIdx.x;
    if (i >= e) return;
    int e64 = flags[1];
    int s = get_edge(edge, e64, i);
    int d = get_edge(edge, e64, (long long)NE + i);
    int slot = atomicAdd(&deg[d], -1) - 1;
    csr[rp[d] + slot] = s;
}

// ---------- all 3 weight transposes + hi/lo splits in one dispatch ----------
__global__ void wsplit_all(const void* __restrict__ W1, const void* __restrict__ W2,
                           const void* __restrict__ W3, const int* __restrict__ flags,
                           unsigned short* __restrict__ Wh1, unsigned short* __restrict__ Wl1,
                           unsigned short* __restrict__ Wh2, unsigned short* __restrict__ Wl2,
                           unsigned short* __restrict__ Wh3, unsigned short* __restrict__ Wl3) {
    int b = blockIdx.x, n = threadIdx.x;
    const void* W; unsigned short *Wh, *Wl; int k, K;
    if (b < 128)      { W = W1; Wh = Wh1; Wl = Wl1; k = b;       K = 128; }
    else if (b < 384) { W = W2; Wh = Wh2; Wl = Wl2; k = b - 128; K = 256; }
    else              { W = W3; Wh = Wh3; Wl = Wl3; k = b - 384; K = 256; }
    float v = get_f(W, flags[0], (size_t)k * 256 + n);
    unsigned short h = f2bf(v);
    Wh[n * K + k] = h;
    Wl[n * K + k] = f2bf(v - bf2f(h));
}

// ---------- pre-aggregation: out[i] = dinv_i * sum_j dinv_j act[j] + dinv_i^2 act[i] ----------
// R6 form (measured best: 75.8us, 46% HBM; R7's 16B/lane variant regressed).
template <int CPL>
__global__ __launch_bounds__(256) void agg_kernel(
    const unsigned short* __restrict__ act, const int* __restrict__ csr,
    const int* __restrict__ rp, const float* __restrict__ dinv,
    unsigned short* __restrict__ out, int n) {
    const int W = CPL * 64;
    int wave = threadIdx.x >> 6;
    int lane = threadIdx.x & 63;
    int gw = blockIdx.x * 4 + wave;
    int nw = gridDim.x * 4;
    int c = lane * CPL;

    for (int node = gw; node < n; node += nw) {
        float acc[CPL];
#pragma unroll
        for (int j = 0; j < CPL; ++j) acc[j] = 0.f;

        int beg = rp[node];
        int end = (node == n - 1) ? NE : rp[node + 1];
        float dn = dinv[node];

        us4 hs4; ushort2 hs2;
        if (CPL == 4) hs4 = *(const us4*)(act + (size_t)node * W + c);
        else          hs2 = *(const ushort2*)(act + (size_t)node * W + c);

        for (int base = beg; base < end; base += 64) {
            int cnt = min(64, end - base);
            int sv = 0; float dv = 0.f;
            if (base + lane < end) {
                sv = csr[base + lane];
                dv = dinv[sv];
            }
            int j = 0;
            for (; j + 3 < cnt; j += 4) {
                int s0 = __builtin_amdgcn_readlane(sv, j);
                int s1 = __builtin_amdgcn_readlane(sv, j + 1);
                int s2 = __builtin_amdgcn_readlane(sv, j + 2);
                int s3 = __builtin_amdgcn_readlane(sv, j + 3);
                float w0 = __int_as_float(__builtin_amdgcn_readlane(__float_as_int(dv), j));
                float w1 = __int_as_float(__builtin_amdgcn_readlane(__float_as_int(dv), j + 1));
                float w2 = __int_as_float(__builtin_amdgcn_readlane(__float_as_int(dv), j + 2));
                float w3 = __int_as_float(__builtin_amdgcn_readlane(__float_as_int(dv), j + 3));
                if (CPL == 4) {
                    us4 h0 = *(const us4*)(act + (size_t)s0 * W + c);
                    us4 h1 = *(const us4*)(act + (size_t)s1 * W + c);
                    us4 h2 = *(const us4*)(act + (size_t)s2 * W + c);
                    us4 h3 = *(const us4*)(act + (size_t)s3 * W + c);
#pragma unroll
                    for (int q = 0; q < 4; ++q)
                        acc[q] += bf2f(h0[q]) * w0 + bf2f(h1[q]) * w1 +
                                  bf2f(h2[q]) * w2 + bf2f(h3[q]) * w3;
                } else {
                    ushort2 h0 = *(const ushort2*)(act + (size_t)s0 * W + c);
                    ushort2 h1 = *(const ushort2*)(act + (size_t)s1 * W + c);
                    ushort2 h2 = *(const ushort2*)(act + (size_t)s2 * W + c);
                    ushort2 h3 = *(const ushort2*)(act + (size_t)s3 * W + c);
                    acc[0] += bf2f(h0.x) * w0 + bf2f(h1.x) * w1 + bf2f(h2.x) * w2 + bf2f(h3.x) * w3;
                    acc[1] += bf2f(h0.y) * w0 + bf2f(h1.y) * w1 + bf2f(h2.y) * w2 + bf2f(h3.y) * w3;
                }
            }
            if (j + 1 < cnt) {
                int s0 = __builtin_amdgcn_readlane(sv, j);
                int s1 = __builtin_amdgcn_readlane(sv, j + 1);
                float w0 = __int_as_float(__builtin_amdgcn_readlane(__float_as_int(dv), j));
                float w1 = __int_as_float(__builtin_amdgcn_readlane(__float_as_int(dv), j + 1));
                if (CPL == 4) {
                    us4 h0 = *(const us4*)(act + (size_t)s0 * W + c);
                    us4 h1 = *(const us4*)(act + (size_t)s1 * W + c);
#pragma unroll
                    for (int q = 0; q < 4; ++q)
                        acc[q] += bf2f(h0[q]) * w0 + bf2f(h1[q]) * w1;
                } else {
                    ushort2 h0 = *(const ushort2*)(act + (size_t)s0 * W + c);
                    ushort2 h1 = *(const ushort2*)(act + (size_t)s1 * W + c);
                    acc[0] += bf2f(h0.x) * w0 + bf2f(h1.x) * w1;
                    acc[1] += bf2f(h0.y) * w0 + bf2f(h1.y) * w1;
                }
                j += 2;
            }
            if (j < cnt) {
                int s0 = __builtin_amdgcn_readlane(sv, j);
                float w0 = __int_as_float(__builtin_amdgcn_readlane(__float_as_int(dv), j));
                if (CPL == 4) {
                    us4 h0 = *(const us4*)(act + (size_t)s0 * W + c);
#pragma unroll
                    for (int q = 0; q < 4; ++q) acc[q] += bf2f(h0[q]) * w0;
                } else {
                    ushort2 h0 = *(const ushort2*)(act + (size_t)s0 * W + c);
                    acc[0] += bf2f(h0.x) * w0;
                    acc[1] += bf2f(h0.y) * w0;
                }
            }
        }

        if (CPL == 4) {
            us4 ov;
#pragma unroll
            for (int j = 0; j < 4; ++j)
                ov[j] = f2bf(acc[j] * dn + bf2f(hs4[j]) * (dn * dn));
            *(us4*)(out + (size_t)node * W + c) = ov;
        } else {
            ushort2 ov;
            ov.x = f2bf(acc[0] * dn + bf2f(hs2.x) * (dn * dn));
            ov.y = f2bf(acc[1] * dn + bf2f(hs2.y) * (dn * dn));
            *(ushort2*)(out + (size_t)node * W + c) = ov;
        }
    }
}

// ---------- GEMM: LDS double-buffered 2-phase (R6 form — measured best) ----------
// Per K-step: issue NEXT tile's 6 global_load_lds into buf^1, ds_read + 32 MFMA
// from buf, ONE __syncthreads. 48KB LDS -> 3 blocks/CU (R8's 3-deep ring at
// 72KB/2 blocks regressed: occupancy was doing the latency hiding).
#define BM 128
#define BK 32
#define PLANE (BM * BK)   // 4096 elems = 8 KB per plane per buffer

__global__ __launch_bounds__(256) void gemm_kernel(
    const unsigned short* __restrict__ A, int K,
    const unsigned short* __restrict__ Wh, const unsigned short* __restrict__ Wl,
    const void* __restrict__ bias, const int* __restrict__ flags,
    int relu, int is_final,
    unsigned short* __restrict__ outb, float* __restrict__ outf, int M) {
    __shared__ __align__(16) unsigned short Ah[2 * PLANE];
    __shared__ __align__(16) unsigned short Bh[2 * PLANE];
    __shared__ __align__(16) unsigned short Bl[2 * PLANE];

    int tid = threadIdx.x;
    int lane = tid & 63;
    int wave = tid >> 6;
    int wm = wave >> 1, wn = wave & 1;
    int row0 = blockIdx.x * BM;
    int col0 = blockIdx.y * 128;
    int f32 = flags[0];

    int srow = lane >> 2;
    int skq = (lane & 3) * 8;
    int ar0 = row0 + wave * 16 + srow;
    int ar1 = row0 + (wave + 4) * 16 + srow;
    ar0 = min(ar0, M - 1);
    ar1 = min(ar1, M - 1);
    const unsigned short* ag0 = A + (size_t)ar0 * K + skq;
    const unsigned short* ag1 = A + (size_t)ar1 * K + skq;
    const unsigned short* bhg0 = Wh + (size_t)(col0 + wave * 16 + srow) * K + skq;
    const unsigned short* bhg1 = Wh + (size_t)(col0 + (wave + 4) * 16 + srow) * K + skq;
    const unsigned short* blg0 = Wl + (size_t)(col0 + wave * 16 + srow) * K + skq;
    const unsigned short* blg1 = Wl + (size_t)(col0 + (wave + 4) * 16 + srow) * K + skq;
    int lo0 = wave * 512;
    int lo1 = (wave + 4) * 512;

    f32x4 acc[4][4];
    for (int mt = 0; mt < 4; ++mt)
        for (int nt = 0; nt < 4; ++nt)
            acc[mt][nt] = (f32x4){0.f, 0.f, 0.f, 0.f};

    // prologue: stage tile 0 into buf 0
    gload16(ag0,  &Ah[lo0]);  gload16(ag1,  &Ah[lo1]);
    gload16(bhg0, &Bh[lo0]);  gload16(bhg1, &Bh[lo1]);
    gload16(blg0, &Bl[lo0]);  gload16(blg1, &Bl[lo1]);
    ag0 += BK; ag1 += BK; bhg0 += BK; bhg1 += BK; blg0 += BK; blg1 += BK;
    __syncthreads();

    int nt_steps = K / BK;
    int kqf = (lane >> 4) * 8;
    for (int t = 0; t < nt_steps; ++t) {
        int cur = (t & 1) * PLANE;
        int nxt = PLANE - cur;
        if (t + 1 < nt_steps) {
            gload16(ag0,  &Ah[nxt + lo0]);  gload16(ag1,  &Ah[nxt + lo1]);
            gload16(bhg0, &Bh[nxt + lo0]);  gload16(bhg1, &Bh[nxt + lo1]);
            gload16(blg0, &Bl[nxt + lo0]);  gload16(blg1, &Bl[nxt + lo1]);
            ag0 += BK; ag1 += BK; bhg0 += BK; bhg1 += BK; blg0 += BK; blg1 += BK;
        }

        bf16x8 af[4], bhf[4], blf[4];
#pragma unroll
        for (int tt = 0; tt < 4; ++tt) {
            int ar = cur + (wm * 64 + tt * 16 + (lane & 15)) * BK + kqf;
            int br = cur + (wn * 64 + tt * 16 + (lane & 15)) * BK + kqf;
            af[tt]  = *(const bf16x8*)&Ah[ar];
            bhf[tt] = *(const bf16x8*)&Bh[br];
            blf[tt] = *(const bf16x8*)&Bl[br];
        }
#pragma unroll
        for (int mt = 0; mt < 4; ++mt)
#pragma unroll
            for (int ntt = 0; ntt < 4; ++ntt) {
                acc[mt][ntt] = __builtin_amdgcn_mfma_f32_16x16x32_bf16(af[mt], bhf[ntt], acc[mt][ntt], 0, 0, 0);
                acc[mt][ntt] = __builtin_amdgcn_mfma_f32_16x16x32_bf16(af[mt], blf[ntt], acc[mt][ntt], 0, 0, 0);
            }
        __syncthreads();
    }

    // C/D layout: col=lane&15 (+16*nt), row=(lane>>4)*4+i
    int wf32 = is_final && f32;
    for (int mt = 0; mt < 4; ++mt)
        for (int ntt = 0; ntt < 4; ++ntt) {
            int col = col0 + wn * 64 + ntt * 16 + (lane & 15);
            float bv = get_f(bias, f32, (size_t)col);
            int rbase = row0 + wm * 64 + mt * 16 + ((lane >> 4) << 2);
            for (int i = 0; i < 4; ++i) {
                int r = rbase + i;
                if (r < M) {
                    float v = acc[mt][ntt][i] + bv;
                    if (relu) v = fmaxf(v, 0.f);
                    if (wf32) outf[(size_t)r * HID + col] = v;
                    else outb[(size_t)r * HID + col] = f2bf(v);
                }
            }
        }
}

// ---------- launch (13 dispatches, was 18) ----------
extern "C" void kernel_launch(void* const* d_in, const int* in_sizes, int n_in,
                              void* d_out, int out_size, void* d_ws, size_t ws_size,
                              hipStream_t stream) {
    const void* x    = d_in[0];
    const void* edge = d_in[1];
    const void* W1   = d_in[2];
    const void* b1   = d_in[3];
    const void* W2   = d_in[4];
    const void* b2   = d_in[5];
    const void* W3   = d_in[6];
    const void* b3   = d_in[7];

    const int N = NN, E = NE;

    char* w = (char*)d_ws;
    auto carve = [&](size_t bytes) -> void* {
        void* p = (void*)w;
        w += (bytes + 255) & ~(size_t)255;
        return p;
    };
    int*   flags = (int*)carve(256);
    int*   deg   = (int*)carve((size_t)N * 4);
    float* dinv  = (float*)carve((size_t)N * 4);
    int*   rp    = (int*)carve((size_t)N * 4);
    int*   bsums = (int*)carve(512);
    int*   csr   = (int*)carve((size_t)E * 4);
    unsigned short* Wh1 = (unsigned short*)carve((size_t)128 * 256 * 2);
    unsigned short* Wl1 = (unsigned short*)carve((size_t)128 * 256 * 2);
    unsigned short* Wh2 = (unsigned short*)carve((size_t)256 * 256 * 2);
    unsigned short* Wl2 = (unsigned short*)carve((size_t)256 * 256 * 2);
    unsigned short* Wh3 = (unsigned short*)carve((size_t)256 * 256 * 2);
    unsigned short* Wl3 = (unsigned short*)carve((size_t)256 * 256 * 2);
    unsigned short* Agg = (unsigned short*)carve((size_t)N * HID * 2);  // 51.2 MB; total ~56.3 MB

    // d_out doubles as scratch until the final GEMM overwrites it:
    //   xb  = bf16 x [N,128] at d_out[0:25.6MB]  (consumed by L1 agg)
    //   act = bf16 [N,256]   at d_out[0:51.2MB]  (layer l output, consumed by layer l+1 agg)
    unsigned short* xb  = (unsigned short*)d_out;
    unsigned short* act = (unsigned short*)d_out;

    int gE = (E + 255) / 256;
    int nb = (N + 1023) / 1024;
    int n4 = N * 128 / 4;
    int gprep = (n4 + 255) / 256;
    dim3 ggemm(782, 2);
    int gagg = 2048;   // persistent: 8 blocks/CU x 4 waves, grid-stride over nodes

    probe_kernel<<<1, 256, 0, stream>>>(W1, edge, flags);
    prep_kernel<<<gprep, 256, 0, stream>>>(x, flags, deg, xb, n4);          // zero + cast
    count_kernel<<<gE, 256, 0, stream>>>(edge, flags, deg, E);
    scanA_kernel<<<nb, 256, 0, stream>>>(deg, rp, bsums, dinv, N);          // scan + dinv
    scanC_kernel<<<nb, 256, 0, stream>>>(rp, bsums, N, nb);                 // local scanB + offset
    fill_kernel<<<gE, 256, 0, stream>>>(edge, flags, rp, deg, csr, E);
    wsplit_all<<<640, 256, 0, stream>>>(W1, W2, W3, flags, Wh1, Wl1, Wh2, Wl2, Wh3, Wl3);

    // ---- layer 1 (K=128) ----
    agg_kernel<2><<<gagg, 256, 0, stream>>>(xb, csr, rp, dinv, Agg, N);
    gemm_kernel<<<ggemm, 256, 0, stream>>>(Agg, 128, Wh1, Wl1, b1, flags, 1, 0, act, nullptr, N);

    // ---- layer 2 (K=256) ----
    agg_kernel<4><<<gagg, 256, 0, stream>>>(act, csr, rp, dinv, Agg, N);
    gemm_kernel<<<ggemm, 256, 0, stream>>>(Agg, 256, Wh2, Wl2, b2, flags, 1, 0, act, nullptr, N);

    // ---- layer 3 (K=256, final) ----
    agg_kernel<4><<<gagg, 256, 0, stream>>>(act, csr, rp, dinv, Agg, N);
    gemm_kernel<<<ggemm, 256, 0, stream>>>(Agg, 256, Wh3, Wl3, b3, flags, 0, 1,
                                           (unsigned short*)d_out, (float*)d_out, N);
}